// Round 5
// baseline (127.915 us; speedup 1.0000x reference)
//
#include <hip/hip_runtime.h>
#include <hip/hip_bf16.h>
#include <stdint.h>

#define KDIM    256
#define NWORDS  1564         // sign words per column: 782 blocks * 2
#define NW      1563         // crossing words (ceil(99999/64))
#define GEMM_GRID 1564       // 782 bm * 2 bn

typedef float  f32x4  __attribute__((ext_vector_type(4)));
typedef __bf16 bf16x8 __attribute__((ext_vector_type(8)));

__device__ __forceinline__ void gl_lds16(const void* g, void* l) {
    __builtin_amdgcn_global_load_lds(
        (const __attribute__((address_space(1))) unsigned int*)g,
        (__attribute__((address_space(3))) unsigned int*)l, 16, 0, 0);
}

// ---------- K0: build W bf16 [512 rows j][512 cols d] ----------
__global__ void build_w(const float* __restrict__ theta,
                        const float* __restrict__ noise,
                        __bf16* __restrict__ W) {
    int idx = blockIdx.x * 256 + threadIdx.x;   // 0..262143
    int j = idx >> 9;
    int d = idx & 511;
    float v;
    if (j < KDIM) v = theta[j * 512 + d];
    else          v = theta[(j - KDIM) * 512 + d] + 0.01f * noise[(j - KDIM) * 512 + d];
    W[idx] = (__bf16)v;
}

// ---------- K1: MFMA GEMM -> packed sign bits ----------
// BM=128 x BN=256, BK=32, 512 threads (8 waves, 2M x 4N, wave-tile 64x64).
// A: global f32 -> regs (issued 1.5 tiles early) -> cvt bf16 -> swizzled
//    ds_write_b128 (LDS holds A as bf16: halves A LDS bytes vs round 4).
// B: global_load_lds DMA, source-granule-swizzled, counted vmcnt.
// Steady state vmcnt(4) drains exactly {A(t+1) regs, B(t) DMA}; loads for
// t+1/t+2 stay in flight across both barriers. 48KB LDS, 2 blocks/CU.
__global__ void __launch_bounds__(512, 4)
gemm_signs(const float* __restrict__ basis,
           const __bf16* __restrict__ W,
           uint64_t* __restrict__ sbits) {
    __shared__ char smem[49152];   // A: [2][128r][64B] @0; B: [2][256c][64B] @16384

    const int tid    = threadIdx.x;
    const int lane   = tid & 63;
    const int wave   = tid >> 6;
    const int wr     = wave >> 2;      // 0..1
    const int wc     = wave & 3;       // 0..3
    const int lane16 = lane & 15;
    const int lgrp   = lane >> 4;

    // bijective XCD swizzle: nwg=1564=8*195+4 (m204): adjacent wgid -> same XCD
    const int orig = blockIdx.x;
    const int xcd  = orig & 7;
    const int wgid = (xcd < 4 ? xcd * 196 : 784 + (xcd - 4) * 195) + (orig >> 3);
    const int bn   = wgid & 1;     // 0..1
    const int bm   = wgid >> 1;    // 0..781

    // ---- A reg-staging geometry: thread -> (row ar, K-octet ah) ----
    const int ar = tid >> 2;           // 0..127
    const int ah = tid & 3;            // 0..3 (8 f32 each)
    int arg = bm * 128 + ar; if (arg > 99999) arg = 99999;   // tail clamp
    const float* abase_g = basis + (size_t)arg * 512 + ah * 8;
    const int awofs = ar * 64 + ((ah ^ (ar & 3)) << 4);      // swizzled LDS byte ofs

    // ---- B DMA staging (round-4 proven path) ----
    auto stage_B = [&](int t) {
        char* bbase = smem + 16384 + ((t & 1) << 14);
        #pragma unroll
        for (int i = 0; i < 2; ++i) {   // cols wave*32+i*16 .. +15, 1KB each
            int c = wave * 32 + i * 16 + (lane >> 2);
            int g = lane & 3;
            const __bf16* src = W + (size_t)(bn * 256 + c) * 512 + t * 32
                                  + ((g ^ ((c >> 1) & 3)) << 3);
            gl_lds16(src, bbase + (wave * 32 + i * 16) * 64);
        }
    };

    f32x4  acc[4][4] = {};
    float4 ra[2][2];                   // A(t) lives in slot t&1

    // ---- prologue: A0, A1 reg loads + B0 DMA; write As[0] ----
    ra[0][0] = *(const float4*)(abase_g);
    ra[0][1] = *(const float4*)(abase_g + 4);
    ra[1][0] = *(const float4*)(abase_g + 32);
    ra[1][1] = *(const float4*)(abase_g + 36);
    stage_B(0);
    asm volatile("s_waitcnt vmcnt(4)" ::: "memory");   // A0 regs ready
    {
        bf16x8 a8;
        a8[0] = (__bf16)ra[0][0].x; a8[1] = (__bf16)ra[0][0].y;
        a8[2] = (__bf16)ra[0][0].z; a8[3] = (__bf16)ra[0][0].w;
        a8[4] = (__bf16)ra[0][1].x; a8[5] = (__bf16)ra[0][1].y;
        a8[6] = (__bf16)ra[0][1].z; a8[7] = (__bf16)ra[0][1].w;
        *(bf16x8*)(smem + awofs) = a8;                 // As[0]
    }

    #pragma unroll
    for (int t = 0; t < 16; ++t) {
        // issue next loads; they stay in flight across both barriers
        if (t < 14) {
            ra[t & 1][0] = *(const float4*)(abase_g + (t + 2) * 32);
            ra[t & 1][1] = *(const float4*)(abase_g + (t + 2) * 32 + 4);
        }
        if (t < 15) stage_B(t + 1);

        // B1: drain {A(t+1) regs, B(t) DMA}; barrier makes tile-t LDS visible
        if      (t < 14) asm volatile("s_waitcnt vmcnt(4)\ns_barrier" ::: "memory");
        else if (t == 14) asm volatile("s_waitcnt vmcnt(2)\ns_barrier" ::: "memory");
        else              asm volatile("s_waitcnt vmcnt(0)\ns_barrier" ::: "memory");

        const char* ab = smem + ((t & 1) << 13);
        const char* bb = smem + 16384 + ((t & 1) << 14);

        bf16x8 bf[4];
        #pragma unroll
        for (int n = 0; n < 4; ++n) {
            int cc = wc * 64 + n * 16 + lane16;
            int gb = lgrp ^ ((cc >> 1) & 3);
            bf[n] = *(const bf16x8*)(bb + cc * 64 + gb * 16);
        }
        bf16x8 af[4];
        #pragma unroll
        for (int m = 0; m < 4; ++m) {
            int rr = wr * 64 + m * 16 + lane16;
            af[m] = *(const bf16x8*)(ab + rr * 64 + ((lgrp ^ (rr & 3)) << 4));
        }

        __builtin_amdgcn_s_setprio(1);
        #pragma unroll
        for (int m = 0; m < 4; ++m)
            #pragma unroll
            for (int n = 0; n < 4; ++n)
                acc[m][n] = __builtin_amdgcn_mfma_f32_16x16x32_bf16(
                    af[m], bf[n], acc[m][n], 0, 0, 0);
        __builtin_amdgcn_s_setprio(0);

        // cvt + write A(t+1) into the opposite-parity buffer (its old readers
        // finished before B2(t-1); its new readers wait for B2(t) below)
        if (t < 15) {
            bf16x8 a8;
            a8[0] = (__bf16)ra[(t + 1) & 1][0].x; a8[1] = (__bf16)ra[(t + 1) & 1][0].y;
            a8[2] = (__bf16)ra[(t + 1) & 1][0].z; a8[3] = (__bf16)ra[(t + 1) & 1][0].w;
            a8[4] = (__bf16)ra[(t + 1) & 1][1].x; a8[5] = (__bf16)ra[(t + 1) & 1][1].y;
            a8[6] = (__bf16)ra[(t + 1) & 1][1].z; a8[7] = (__bf16)ra[(t + 1) & 1][1].w;
            *(bf16x8*)(smem + (((t + 1) & 1) << 13) + awofs) = a8;
        }

        // B2: A-writes visible; gates next iter's DMA/ds_write overwrites
        asm volatile("s_waitcnt lgkmcnt(0)\ns_barrier" ::: "memory");
    }

    // ---- epilogue: sign bytes -> LDS transpose -> multiply-pack -> u64 ----
    // C/D layout: col = lane&15, row = (lane>>4)*4 + reg
    unsigned char* sb = (unsigned char*)smem;     // [256 cols][136B] = 34.8KB
    #pragma unroll
    for (int m = 0; m < 4; ++m) {
        #pragma unroll
        for (int n = 0; n < 4; ++n) {
            int cc = wc * 64 + n * 16 + lane16;          // local col 0..255
            int rb = wr * 64 + m * 16 + lgrp * 4;        // local row base 0..124
            uint32_t pk = 0;
            #pragma unroll
            for (int r = 0; r < 4; ++r)
                pk |= (acc[m][n][r] < 0.0f ? 1u : 0u) << (8 * r);
            *(uint32_t*)&sb[cc * 136 + rb] = pk;
        }
    }
    asm volatile("s_waitcnt lgkmcnt(0)\ns_barrier" ::: "memory");

    {   // thread -> (col 0..255, word-half 0..1); 64 sign bytes -> u64
        const int col = tid & 255;
        const int wh  = tid >> 8;
        const unsigned char* src = &sb[col * 136 + wh * 64];
        uint64_t wbits = 0;
        #pragma unroll
        for (int k = 0; k < 16; ++k) {
            uint32_t q  = *(const uint32_t*)&src[4 * k];
            uint32_t p4 = ((q & 0x01010101u) * 0x10204080u) >> 28;
            wbits |= (uint64_t)p4 << (4 * k);
        }
        sbits[(size_t)(bm * 2 + wh) * 512 + bn * 256 + col] = wbits;  // coalesced
    }
}

// ---------- K2: crossing masks from sign bits ----------
__global__ void crossing_masks(const uint64_t* __restrict__ sbits,
                               uint64_t* __restrict__ maskT) {
    const int w = blockIdx.x;       // 0..1562
    const int j = threadIdx.x;      // 0..255
    uint64_t s0r = sbits[(size_t)w * 512 + j];
    uint64_t s0p = sbits[(size_t)w * 512 + 256 + j];
    uint64_t s1r = sbits[(size_t)(w + 1) * 512 + j];
    uint64_t s1p = sbits[(size_t)(w + 1) * 512 + 256 + j];
    uint64_t cr = s0r ^ ((s0r >> 1) | (s1r << 63));
    uint64_t cp = s0p ^ ((s0p >> 1) | (s1p << 63));
    uint64_t m = cr & cp;
    if (w == NW - 1) m &= 0x7FFFFFFFull;    // 31 valid crossings in last word
    maskT[(size_t)w * 256 + j] = m;
}

// ---------- K3: pairwise AND-popcount ----------
__global__ void zero_out(float* __restrict__ out) {
    int i = blockIdx.x * 256 + threadIdx.x;
    if (i < 32640) out[i] = 0.0f;
}

__global__ void pair_popcount(const uint64_t* __restrict__ maskT,
                              float* __restrict__ out) {
    const int i = blockIdx.x;   // 0..255
    const int c = blockIdx.y;   // 0..7 word chunk
    const int j = threadIdx.x;  // 0..255
    if (j <= i) return;
    int w0 = c * 196;
    int w1 = w0 + 196; if (w1 > NW) w1 = NW;
    uint32_t sum = 0;
    #pragma unroll 4
    for (int w = w0; w < w1; ++w) {
        uint64_t mi = maskT[(size_t)w * 256 + i];   // block-uniform -> scalar
        uint64_t mj = maskT[(size_t)w * 256 + j];   // coalesced
        sum += (uint32_t)__popcll(mi & mj);
    }
    const size_t idx = (size_t)i * (2 * KDIM - i - 1) / 2 + (size_t)(j - i - 1);
    atomicAdd(&out[idx], (float)sum);   // exact-integer f32 adds -> deterministic
}

extern "C" void kernel_launch(void* const* d_in, const int* in_sizes, int n_in,
                              void* d_out, int out_size, void* d_ws, size_t ws_size,
                              hipStream_t stream) {
    const float* theta = (const float*)d_in[0];   // [256,512]
    const float* basis = (const float*)d_in[1];   // [100000,512]
    const float* noise = (const float*)d_in[2];   // [256,512]
    float* out = (float*)d_out;                   // [32640]

    char* ws = (char*)d_ws;
    __bf16*   W     = (__bf16*)ws;                              // 512 KB
    uint64_t* sbits = (uint64_t*)(ws + 524288);                 // 1564*512*8 = 6.41 MB
    uint64_t* maskT = (uint64_t*)(ws + 524288 + (size_t)NWORDS * 512 * 8); // 3.2 MB

    hipLaunchKernelGGL(build_w,        dim3(1024),     dim3(256), 0, stream, theta, noise, W);
    hipLaunchKernelGGL(gemm_signs,     dim3(GEMM_GRID),dim3(512), 0, stream, basis, W, sbits);
    hipLaunchKernelGGL(crossing_masks, dim3(NW),       dim3(256), 0, stream, sbits, maskT);
    hipLaunchKernelGGL(zero_out,       dim3(128),      dim3(256), 0, stream, out);
    hipLaunchKernelGGL(pair_popcount,  dim3(KDIM, 8),  dim3(256), 0, stream, maskT, out);
}